// Round 4
// baseline (425.349 us; speedup 1.0000x reference)
//
#include <hip/hip_runtime.h>
#include <cstdint>
#include <cstddef>

// Problem constants (fixed by the reference)
#define TOKENS 8192
#define INF    4096
#define OUTF   4096

typedef int v4i __attribute__((ext_vector_type(4)));

// ---------------------------------------------------------------------------
// Kernel 1: pack int32 -> int8 into workspace (x8 then w8, row-major).
// x: 8192x4096 ints -> 32MB i8 ; w: 4096x4096 ints -> 16MB i8. ws needs 48MB.
// ---------------------------------------------------------------------------
__global__ __launch_bounds__(256) void pack_i8_kernel(
    const int* __restrict__ xi, const int* __restrict__ wi,
    uint8_t* __restrict__ x8, uint8_t* __restrict__ w8) {
  const int NX = (TOKENS * INF) / 4;   // 8388608 chunks of 4 ints (x)
  const int NT = 2048 * 256;           // total threads = 524288
  int tid = blockIdx.x * 256 + threadIdx.x;
#pragma unroll 1
  for (int it = 0; it < 24; ++it) {    // 24 * 524288 = 12582912 = all chunks
    int c = it * NT + tid;
    const int4* src;
    unsigned* dst;
    if (c < NX) {
      src = (const int4*)xi + c;
      dst = (unsigned*)x8 + c;
    } else {
      int c2 = c - NX;
      src = (const int4*)wi + c2;
      dst = (unsigned*)w8 + c2;
    }
    int4 v = *src;
    *dst = (v.x & 255) | ((v.y & 255) << 8) | ((v.z & 255) << 16) |
           (((unsigned)v.w) << 24);
  }
}

// ---------------------------------------------------------------------------
// Branchless exact-GeLU via Abramowitz-Stegun 7.1.26 erf (|err| <= 1.5e-7).
// ---------------------------------------------------------------------------
__device__ __forceinline__ float gelu_exact(float y) {
  float x = y * 0.70710678118654752f;   // y / sqrt(2)
  float s = fabsf(x);
  float t = __builtin_amdgcn_rcpf(fmaf(s, 0.3275911f, 1.0f));
  float p = t * fmaf(t, fmaf(t, fmaf(t, fmaf(t, 1.061405429f, -1.453152027f),
                                     1.421413741f), -0.284496736f),
                     0.254829592f);
  float e = __expf(-s * s);
  float er = fmaf(-p, e, 1.0f);         // erf(|x|)
  er = copysignf(er, x);
  return 0.5f * y * (1.0f + er);
}

__device__ __forceinline__ void barrier_fenced() {
  asm volatile("" ::: "memory");
  __builtin_amdgcn_s_barrier();
  asm volatile("" ::: "memory");
}

// ---------------------------------------------------------------------------
// Kernel 2: int8 GEMM, BM=BN=256, BK=128 (bytes), 512 threads / 8 waves (2x4),
// wave tile 128x64 via 8x4 frags of mfma_i32_16x16x64_i8.
//
// T-stack structure (m201-derived, adapted to i8 / 4 phases per K-tile):
//  - global_load_lds (16B) staging, LINEAR LDS dest; XOR chunk-swizzle
//    realized by inverse-permuting the per-lane GLOBAL source (rule #21).
//    Chunk (row r, global slot s_g) lives at LDS slot s_g ^ (r&7) -> both
//    ds_read_b128 sides conflict-free (verified 0 conflicts in R2).
//  - Double-buffered 128KB LDS; tile t+2's 8 loads burst-issued after tile
//    t's last read-barrier; loop-top s_waitcnt vmcnt(8) (counted, never 0
//    in main loop) + raw s_barrier (no auto-drain).
//  - 4 phases per K-tile: {ds_read subtile; barrier; lgkmcnt(0); setprio(1);
//    16 MFMA; setprio(0); barrier}. B frags reused across adjacent phases.
// Output: int32 elements.
// ---------------------------------------------------------------------------
__global__ __launch_bounds__(512, 2) void gemm_i8_gelu_q_kernel(
    const uint8_t* __restrict__ x8, const uint8_t* __restrict__ w8,
    const float* __restrict__ bias, const float* __restrict__ pa,
    const float* __restrict__ pb, int* __restrict__ out) {
  __shared__ char sm[131072];          // buf b: A at b*65536, B at +32768

  const int tid = threadIdx.x;
  const int l   = tid & 63;
  const int wv  = tid >> 6;
  const int wr  = wv >> 2;             // 0..1  (M wave row)
  const int wc  = wv & 3;              // 0..3  (N wave col)
  const int lr  = l & 15;              // fragment row
  const int lg  = l >> 4;              // k-group 0..3

  // XCD-aware bijective swizzle (512 blocks % 8 == 0)
  int id = blockIdx.x;
  int wg = (id & 7) * 64 + (id >> 3);
  const int m0 = (wg >> 4) * 256;      // 32 row-bands
  const int n0 = (wg & 15) * 256;      // 16 col-bands

  const float av = pa[0];
  const float bv = pb[0];

  // ---- staging addressing: wave wv, instr i covers LDS rows 8*(wv*4+i)+0..7
  // HW writes uniform_base + lane*16: lane l -> row +(l>>3), LDS slot l&7.
  // LDS slot s_l holds global chunk s_g = s_l ^ (row&7); row&7 = (l>>3)&7.
  const int grow = (wv << 5) + (l >> 3);                 // + i*8
  const int gch  = ((l & 7) ^ ((l >> 3) & 7)) << 4;
  const uint8_t* gA = x8 + (size_t)(m0 + grow) * INF + gch;
  const uint8_t* gB = w8 + (size_t)(n0 + grow) * INF + gch;
  const int ldsw = (wv << 2) * 1024;                     // + i*1024

  // ---- fragment read offsets (row&7 == l&7 for all frag rows) ----
  int aoff[8], boff[4], sb[2];
#pragma unroll
  for (int m = 0; m < 8; ++m) aoff[m] = (wr * 128 + m * 16 + lr) * 128;
#pragma unroll
  for (int n = 0; n < 4; ++n) boff[n] = 32768 + (wc * 64 + n * 16 + lr) * 128;
#pragma unroll
  for (int s = 0; s < 2; ++s) sb[s] = (((s * 4 + lg) ^ (l & 7)) << 4);

  v4i acc[8][4];
#pragma unroll
  for (int m = 0; m < 8; ++m)
#pragma unroll
    for (int n = 0; n < 4; ++n) acc[m][n] = (v4i){0, 0, 0, 0};

#define BURST(kt, bo)                                                         \
  {                                                                           \
    _Pragma("unroll")                                                         \
    for (int i = 0; i < 4; ++i) {                                             \
      __builtin_amdgcn_global_load_lds(                                       \
          (const __attribute__((address_space(1))) unsigned*)(                \
              gA + (size_t)i * 8 * INF + (size_t)(kt) * 128),                 \
          (__attribute__((address_space(3))) unsigned*)(sm + (bo) + ldsw +    \
                                                        i * 1024),            \
          16, 0, 0);                                                          \
      __builtin_amdgcn_global_load_lds(                                       \
          (const __attribute__((address_space(1))) unsigned*)(                \
              gB + (size_t)i * 8 * INF + (size_t)(kt) * 128),                 \
          (__attribute__((address_space(3))) unsigned*)(sm + (bo) + 32768 +   \
                                                        ldsw + i * 1024),     \
          16, 0, 0);                                                          \
    }                                                                         \
  }

#define LDV4(off) (*(const v4i*)(sm + bo + (off)))

#define PHASE(mb, ks, READB)                                                  \
  {                                                                           \
    if (READB) {                                                              \
      _Pragma("unroll")                                                       \
      for (int n = 0; n < 4; ++n) Bf[n] = LDV4(boff[n] + sb[ks]);             \
    }                                                                         \
    v4i A0 = LDV4(aoff[(mb) + 0] + sb[ks]);                                   \
    v4i A1 = LDV4(aoff[(mb) + 1] + sb[ks]);                                   \
    v4i A2 = LDV4(aoff[(mb) + 2] + sb[ks]);                                   \
    v4i A3 = LDV4(aoff[(mb) + 3] + sb[ks]);                                   \
    barrier_fenced();                                                         \
    asm volatile("s_waitcnt lgkmcnt(0)" ::: "memory");                        \
    __builtin_amdgcn_s_setprio(1);                                            \
    _Pragma("unroll")                                                         \
    for (int n = 0; n < 4; ++n) {                                             \
      acc[(mb) + 0][n] = __builtin_amdgcn_mfma_i32_16x16x64_i8(               \
          A0, Bf[n], acc[(mb) + 0][n], 0, 0, 0);                              \
      acc[(mb) + 1][n] = __builtin_amdgcn_mfma_i32_16x16x64_i8(               \
          A1, Bf[n], acc[(mb) + 1][n], 0, 0, 0);                              \
      acc[(mb) + 2][n] = __builtin_amdgcn_mfma_i32_16x16x64_i8(               \
          A2, Bf[n], acc[(mb) + 2][n], 0, 0, 0);                              \
      acc[(mb) + 3][n] = __builtin_amdgcn_mfma_i32_16x16x64_i8(               \
          A3, Bf[n], acc[(mb) + 3][n], 0, 0, 0);                              \
    }                                                                         \
    __builtin_amdgcn_s_setprio(0);                                            \
    __builtin_amdgcn_s_barrier();                                             \
    asm volatile("" ::: "memory");                                            \
  }

  // prologue: tiles 0 and 1 in flight
  BURST(0, 0);
  BURST(1, 65536);

  const int NKT = INF / 128;           // 32 K-tiles
#pragma unroll 1
  for (int kt = 0; kt < NKT; ++kt) {
    const int bo = (kt & 1) << 16;
    if (kt < NKT - 1) {
      asm volatile("s_waitcnt vmcnt(8)" ::: "memory");  // tile kt landed,
    } else {                                            // kt+1's 8 in flight
      asm volatile("s_waitcnt vmcnt(0)" ::: "memory");  // final tile: drain
    }
    barrier_fenced();                  // all waves' loads for tile kt done

    v4i Bf[4];
    PHASE(0, 0, 1)                     // k0, m0-3 (reads B@k0)
    PHASE(4, 0, 0)                     // k0, m4-7 (reuses B)
    PHASE(0, 1, 1)                     // k1, m0-3 (reads B@k1)
    PHASE(4, 1, 0)                     // k1, m4-7
    // all waves past reads of buf[kt&1] (last PHASE barrier) -> refill it
    if (kt + 2 < NKT) BURST(kt + 2, bo);
  }

  // ---- epilogue: dequant + bias + exact GeLU + requant, write INT32 ----
  float bvals[4];
#pragma unroll
  for (int n = 0; n < 4; ++n) bvals[n] = bias[n0 + wc * 64 + n * 16 + lr];

#pragma unroll
  for (int m = 0; m < 8; ++m) {
    int rowb = m0 + wr * 128 + m * 16 + lg * 4;
#pragma unroll
    for (int q = 0; q < 4; ++q) {
      size_t rb = (size_t)(rowb + q) * OUTF;
#pragma unroll
      for (int n = 0; n < 4; ++n) {
        float f = fmaf(av, (float)acc[m][n][q], bvals[n]);
        float g = gelu_exact(f);
        float r = __builtin_rintf(g * bv);
        r = fminf(fmaxf(r, -128.0f), 127.0f);
        out[rb + (size_t)(n0 + wc * 64 + n * 16 + lr)] = (int)r;
      }
    }
  }
#undef BURST
#undef LDV4
#undef PHASE
}

// ---------------------------------------------------------------------------
extern "C" void kernel_launch(void* const* d_in, const int* in_sizes, int n_in,
                              void* d_out, int out_size, void* d_ws,
                              size_t ws_size, hipStream_t stream) {
  const int*   xi   = (const int*)d_in[0];
  const int*   wi   = (const int*)d_in[1];
  const float* bias = (const float*)d_in[2];
  const float* pa   = (const float*)d_in[3];
  const float* pb   = (const float*)d_in[4];
  int*         out  = (int*)d_out;

  uint8_t* x8 = (uint8_t*)d_ws;                         // 33554432 B
  uint8_t* w8 = x8 + (size_t)TOKENS * INF;              // 16777216 B
  // requires ws_size >= 50331648

  pack_i8_kernel<<<2048, 256, 0, stream>>>(xi, wi, x8, w8);

  dim3 grid((TOKENS / 256) * (OUTF / 256));             // 512 blocks
  gemm_i8_gelu_q_kernel<<<grid, 512, 0, stream>>>(x8, w8, bias, pa, pb, out);
}

// Round 5
// 411.919 us; speedup vs baseline: 1.0326x; 1.0326x over previous
//
#include <hip/hip_runtime.h>
#include <cstdint>
#include <cstddef>

// Problem constants (fixed by the reference)
#define TOKENS 8192
#define INF    4096
#define OUTF   4096

typedef int v4i __attribute__((ext_vector_type(4)));

// ---------------------------------------------------------------------------
// Kernel 1: pack int32 -> int8 into workspace (x8 then w8, row-major).
// Batched 4-wide loads for ILP (was serial unroll-1, latency-bound).
// ---------------------------------------------------------------------------
__global__ __launch_bounds__(256) void pack_i8_kernel(
    const int* __restrict__ xi, const int* __restrict__ wi,
    uint8_t* __restrict__ x8, uint8_t* __restrict__ w8) {
  const int NX = (TOKENS * INF) / 4;   // 8388608 x-chunks of 4 ints
  const int NT = 2048 * 256;           // 524288 threads
  int tid = blockIdx.x * 256 + threadIdx.x;
#pragma unroll 1
  for (int g = 0; g < 6; ++g) {        // 6 groups x 4 chunks = 24/thread
    int c[4];
    int4 v[4];
#pragma unroll
    for (int j = 0; j < 4; ++j) {      // 4 independent loads in flight
      c[j] = (g * 4 + j) * NT + tid;
      const int4* src = (c[j] < NX) ? ((const int4*)xi + c[j])
                                    : ((const int4*)wi + (c[j] - NX));
      v[j] = *src;
    }
#pragma unroll
    for (int j = 0; j < 4; ++j) {
      unsigned* dst = (c[j] < NX) ? ((unsigned*)x8 + c[j])
                                  : ((unsigned*)w8 + (c[j] - NX));
      *dst = (v[j].x & 255) | ((v[j].y & 255) << 8) | ((v[j].z & 255) << 16) |
             (((unsigned)v[j].w) << 24);
    }
  }
}

// ---------------------------------------------------------------------------
// Branchless exact-GeLU via Abramowitz-Stegun 7.1.26 erf (|err| <= 1.5e-7).
// ---------------------------------------------------------------------------
__device__ __forceinline__ float gelu_exact(float y) {
  float x = y * 0.70710678118654752f;   // y / sqrt(2)
  float s = fabsf(x);
  float t = __builtin_amdgcn_rcpf(fmaf(s, 0.3275911f, 1.0f));
  float p = t * fmaf(t, fmaf(t, fmaf(t, fmaf(t, 1.061405429f, -1.453152027f),
                                     1.421413741f), -0.284496736f),
                     0.254829592f);
  float e = __expf(-s * s);
  float er = fmaf(-p, e, 1.0f);         // erf(|x|)
  er = copysignf(er, x);
  return 0.5f * y * (1.0f + er);
}

__device__ __forceinline__ void barrier_fenced() {
  asm volatile("" ::: "memory");
  __builtin_amdgcn_s_barrier();
  asm volatile("" ::: "memory");
}

// ---------------------------------------------------------------------------
// Kernel 2: int8 GEMM, BM=BN=256, 512 threads / 8 waves (2x4), wave tile
// 128x64, mfma_i32_16x16x64_i8. m201-faithful fine-phase schedule:
//
//  - LDS: ring of 4 K-half slots (K=64B): A slot s at s*16KB, B at 64KB+s*16KB
//    (128 KB total). Half h lives in slot h&3.
//  - 4 phases per half, each: {ds_read frags ; 1 global_load_lds slot staging
//    half h+3 (into slot (h+3)&3 = (h-1)&3, free since the barrier ending
//    half h-1) ; barrier ; lgkmcnt(0) ; setprio(1) ; 8 MFMA ; setprio(0) ;
//    barrier}.  Fine ds_read || G-load || MFMA interleave per m196/m201.
//  - One counted s_waitcnt vmcnt(8) per half (end of P4) guaranteeing half
//    h+1 landed; tail peels to vmcnt(4)/vmcnt(0). Never drains mid-loop.
//  - 4-way XOR swizzle on 64B rows: LDS[r][c] = G[r][c^(r&3)] (16B chunks);
//    realized via inverse-permuted GLOBAL source + linear gll dest (rule 21).
// Output: int32 elements.
// ---------------------------------------------------------------------------
__global__ __launch_bounds__(512, 2) void gemm_i8_gelu_q_kernel(
    const uint8_t* __restrict__ x8, const uint8_t* __restrict__ w8,
    const float* __restrict__ bias, const float* __restrict__ pa,
    const float* __restrict__ pb, int* __restrict__ out) {
  __shared__ char sm[131072];

  const int tid = threadIdx.x;
  const int l   = tid & 63;
  const int wv  = tid >> 6;
  const int wr  = wv >> 2;             // 0..1  (M wave row)
  const int wc  = wv & 3;              // 0..3  (N wave col)
  const int lr  = l & 15;              // fragment row
  const int lg  = l >> 4;              // k-group 0..3 (16B chunk within K=64)

  // XCD-aware bijective swizzle (512 blocks % 8 == 0)
  int id = blockIdx.x;
  int wg = (id & 7) * 64 + (id >> 3);
  const int m0 = (wg >> 4) * 256;      // 32 row-bands
  const int n0 = (wg & 15) * 256;      // 16 col-bands

  const float av = pa[0];
  const float bv = pb[0];

  // ---- staging addressing ----
  // gll slot j of half h: wave wv writes rows j*128 + wv*16 + (l>>2),
  // LDS chunk l&3 (linear dest). Source chunk = (l&3) ^ (row&3),
  // row&3 = (l>>2)&3  ->  LDS[r][c] = G[r][c ^ (r&3)].
  const int srow4 = l >> 2;                              // 0..15
  const int schu  = ((l & 3) ^ (srow4 & 3)) << 4;
  const uint8_t* bA = x8 + (size_t)(m0 + wv * 16 + srow4) * INF + schu;
  const uint8_t* bB = w8 + (size_t)(n0 + wv * 16 + srow4) * INF + schu;
  const int dA = wv * 1024;            // + slot*16384 + j*8192 (+65536 for B)

  // ---- fragment read offsets: row = band + lr, chunk lg -> LDS chunk
  // lg ^ (lr&3) (frag base rows are multiples of 16) ----
  int aoff[8], boff[4];
#pragma unroll
  for (int m = 0; m < 8; ++m)
    aoff[m] = (wr * 128 + m * 16 + lr) * 64 + ((lg ^ (lr & 3)) << 4);
#pragma unroll
  for (int n = 0; n < 4; ++n)
    boff[n] = 65536 + (wc * 64 + n * 16 + lr) * 64 + ((lg ^ (lr & 3)) << 4);

  v4i acc[8][4];
#pragma unroll
  for (int m = 0; m < 8; ++m)
#pragma unroll
    for (int n = 0; n < 4; ++n) acc[m][n] = (v4i){0, 0, 0, 0};

#define GLL(gsrc, ldst)                                                       \
  __builtin_amdgcn_global_load_lds(                                           \
      (const __attribute__((address_space(1))) unsigned*)(gsrc),              \
      (__attribute__((address_space(3))) unsigned*)(ldst), 16, 0, 0);

  // stage half H, gll slot j:  A j: src bA + H*64 + j*128*INF,
  //                            dst slot(H&3) + j*8192 + dA  (B: +65536)
#define GLA(H, J) GLL(bA + (size_t)(H) * 64 + (size_t)(J) * 128 * INF,        \
                      sm + (((H) & 3) << 14) + (J) * 8192 + dA)
#define GLB(H, J) GLL(bB + (size_t)(H) * 64 + (size_t)(J) * 128 * INF,        \
                      sm + 65536 + (((H) & 3) << 14) + (J) * 8192 + dA)

#define MM(m, n) acc[m][n] = __builtin_amdgcn_mfma_i32_16x16x64_i8(           \
                     Af[m], Bf[n], acc[m][n], 0, 0, 0)

#define PRE_MFMA                                                              \
  barrier_fenced();                                                           \
  asm volatile("s_waitcnt lgkmcnt(0)" ::: "memory");                          \
  __builtin_amdgcn_s_setprio(1);
#define POST_MFMA                                                             \
  __builtin_amdgcn_s_setprio(0);                                              \
  barrier_fenced();

  // One K-half = one MFMA kstep (K=64). 4 phases x 8 MFMA.
  // NW: vmcnt immediate at end of half (8 main, 4/0 tail, -1 = none).
#define HALF(H, S, DOSTAGE, NW)                                               \
  {                                                                           \
    const char* sb_ = sm + ((S) << 14);                                       \
    v4i Af[8], Bf[4];                                                         \
    /* P1: A0-3,B0-1 reads ; stage A j0 */                                    \
    Af[0] = *(const v4i*)(sb_ + aoff[0]);                                     \
    Af[1] = *(const v4i*)(sb_ + aoff[1]);                                     \
    Af[2] = *(const v4i*)(sb_ + aoff[2]);                                     \
    Af[3] = *(const v4i*)(sb_ + aoff[3]);                                     \
    Bf[0] = *(const v4i*)(sb_ + boff[0]);                                     \
    Bf[1] = *(const v4i*)(sb_ + boff[1]);                                     \
    if (DOSTAGE) { GLA((H) + 3, 0); }                                         \
    PRE_MFMA                                                                  \
    MM(0, 0); MM(0, 1); MM(1, 0); MM(1, 1);                                   \
    MM(2, 0); MM(2, 1); MM(3, 0); MM(3, 1);                                   \
    POST_MFMA                                                                 \
    /* P2: A4-7 reads ; stage A j1 */                                         \
    Af[4] = *(const v4i*)(sb_ + aoff[4]);                                     \
    Af[5] = *(const v4i*)(sb_ + aoff[5]);                                     \
    Af[6] = *(const v4i*)(sb_ + aoff[6]);                                     \
    Af[7] = *(const v4i*)(sb_ + aoff[7]);                                     \
    if (DOSTAGE) { GLA((H) + 3, 1); }                                         \
    PRE_MFMA                                                                  \
    MM(4, 0); MM(4, 1); MM(5, 0); MM(5, 1);                                   \
    MM(6, 0); MM(6, 1); MM(7, 0); MM(7, 1);                                   \
    POST_MFMA                                                                 \
    /* P3: B2-3 reads ; stage B j0 */                                         \
    Bf[2] = *(const v4i*)(sb_ + boff[2]);                                     \
    Bf[3] = *(const v4i*)(sb_ + boff[3]);                                     \
    if (DOSTAGE) { GLB((H) + 3, 0); }                                         \
    PRE_MFMA                                                                  \
    MM(0, 2); MM(0, 3); MM(1, 2); MM(1, 3);                                   \
    MM(2, 2); MM(2, 3); MM(3, 2); MM(3, 3);                                   \
    POST_MFMA                                                                 \
    /* P4: stage B j1 ; end-of-half counted vmcnt publishes half H+1 */       \
    if (DOSTAGE) { GLB((H) + 3, 1); }                                         \
    barrier_fenced();                                                         \
    __builtin_amdgcn_s_setprio(1);                                            \
    MM(4, 2); MM(4, 3); MM(5, 2); MM(5, 3);                                   \
    MM(6, 2); MM(6, 3); MM(7, 2); MM(7, 3);                                   \
    __builtin_amdgcn_s_setprio(0);                                            \
    if ((NW) == 8) { asm volatile("s_waitcnt vmcnt(8)" ::: "memory"); }       \
    else if ((NW) == 4) { asm volatile("s_waitcnt vmcnt(4)" ::: "memory"); }  \
    else if ((NW) == 0) { asm volatile("s_waitcnt vmcnt(0)" ::: "memory"); }  \
    if ((NW) >= 0) { barrier_fenced(); }                                      \
  }

  // ---- prologue: stage halves 0,1,2 (12 gll, 4 per half, in half order) ----
#pragma unroll
  for (int hh = 0; hh < 3; ++hh) {
    GLA(hh, 0); GLA(hh, 1); GLB(hh, 0); GLB(hh, 1);
  }
  asm volatile("s_waitcnt vmcnt(8)" ::: "memory");   // half 0 landed
  barrier_fenced();

  // ---- main: 64 K-halves; stage stops at h=60 (stages half 63) ----
#pragma unroll 1
  for (int hb = 0; hb < 60; hb += 4) {
    HALF(hb + 0, 0, 1, 8)
    HALF(hb + 1, 1, 1, 8)
    HALF(hb + 2, 2, 1, 8)
    HALF(hb + 3, 3, 1, 8)
  }
  HALF(60, 0, 1, 8)
  HALF(61, 1, 0, 4)
  HALF(62, 2, 0, 0)
  HALF(63, 3, 0, -1)

  // ---- epilogue: dequant + bias + exact GeLU + requant, write INT32 ----
  float bvals[4];
#pragma unroll
  for (int n = 0; n < 4; ++n) bvals[n] = bias[n0 + wc * 64 + n * 16 + lr];

#pragma unroll
  for (int m = 0; m < 8; ++m) {
    int rowb = m0 + wr * 128 + m * 16 + lg * 4;
#pragma unroll
    for (int q = 0; q < 4; ++q) {
      size_t rb = (size_t)(rowb + q) * OUTF;
#pragma unroll
      for (int n = 0; n < 4; ++n) {
        float f = fmaf(av, (float)acc[m][n][q], bvals[n]);
        float g = gelu_exact(f);
        float r = __builtin_rintf(g * bv);
        r = fminf(fmaxf(r, -128.0f), 127.0f);
        out[rb + (size_t)(n0 + wc * 64 + n * 16 + lr)] = (int)r;
      }
    }
  }
#undef GLL
#undef GLA
#undef GLB
#undef MM
#undef PRE_MFMA
#undef POST_MFMA
#undef HALF
}

// ---------------------------------------------------------------------------
extern "C" void kernel_launch(void* const* d_in, const int* in_sizes, int n_in,
                              void* d_out, int out_size, void* d_ws,
                              size_t ws_size, hipStream_t stream) {
  const int*   xi   = (const int*)d_in[0];
  const int*   wi   = (const int*)d_in[1];
  const float* bias = (const float*)d_in[2];
  const float* pa   = (const float*)d_in[3];
  const float* pb   = (const float*)d_in[4];
  int*         out  = (int*)d_out;

  uint8_t* x8 = (uint8_t*)d_ws;                         // 33554432 B
  uint8_t* w8 = x8 + (size_t)TOKENS * INF;              // 16777216 B
  // requires ws_size >= 50331648

  pack_i8_kernel<<<2048, 256, 0, stream>>>(xi, wi, x8, w8);

  dim3 grid((TOKENS / 256) * (OUTF / 256));             // 512 blocks
  gemm_i8_gelu_q_kernel<<<grid, 512, 0, stream>>>(x8, w8, bias, pa, pb, out);
}

// Round 7
// 400.185 us; speedup vs baseline: 1.0629x; 1.0293x over previous
//
#include <hip/hip_runtime.h>
#include <cstdint>
#include <cstddef>

// Problem constants (fixed by the reference)
#define TOKENS 8192
#define INF    4096
#define OUTF   4096

typedef int v4i __attribute__((ext_vector_type(4)));

// ---------------------------------------------------------------------------
// Kernel 1: pack int32 -> int8 into workspace (x8 then w8, row-major).
// ---------------------------------------------------------------------------
__global__ __launch_bounds__(256) void pack_i8_kernel(
    const int* __restrict__ xi, const int* __restrict__ wi,
    uint8_t* __restrict__ x8, uint8_t* __restrict__ w8) {
  const int NX = (TOKENS * INF) / 4;   // 8388608 x-chunks of 4 ints
  const int NT = 2048 * 256;           // 524288 threads
  int tid = blockIdx.x * 256 + threadIdx.x;
#pragma unroll 1
  for (int g = 0; g < 6; ++g) {        // 6 groups x 4 chunks = 24/thread
    int c[4];
    int4 v[4];
#pragma unroll
    for (int j = 0; j < 4; ++j) {      // 4 independent loads in flight
      c[j] = (g * 4 + j) * NT + tid;
      const int4* src = (c[j] < NX) ? ((const int4*)xi + c[j])
                                    : ((const int4*)wi + (c[j] - NX));
      v[j] = *src;
    }
#pragma unroll
    for (int j = 0; j < 4; ++j) {
      unsigned* dst = (c[j] < NX) ? ((unsigned*)x8 + c[j])
                                  : ((unsigned*)w8 + (c[j] - NX));
      *dst = (v[j].x & 255) | ((v[j].y & 255) << 8) | ((v[j].z & 255) << 16) |
             (((unsigned)v[j].w) << 24);
    }
  }
}

// ---------------------------------------------------------------------------
// Branchless exact-GeLU via Abramowitz-Stegun 7.1.26 erf (|err| <= 1.5e-7).
// ---------------------------------------------------------------------------
__device__ __forceinline__ float gelu_exact(float y) {
  float x = y * 0.70710678118654752f;   // y / sqrt(2)
  float s = fabsf(x);
  float t = __builtin_amdgcn_rcpf(fmaf(s, 0.3275911f, 1.0f));
  float p = t * fmaf(t, fmaf(t, fmaf(t, fmaf(t, 1.061405429f, -1.453152027f),
                                     1.421413741f), -0.284496736f),
                     0.254829592f);
  float e = __expf(-s * s);
  float er = fmaf(-p, e, 1.0f);         // erf(|x|)
  er = copysignf(er, x);
  return 0.5f * y * (1.0f + er);
}

__device__ __forceinline__ void barrier_fenced() {
  asm volatile("" ::: "memory");
  __builtin_amdgcn_s_barrier();
  asm volatile("" ::: "memory");
}

// ---------------------------------------------------------------------------
// Kernel 2: int8 GEMM, BM=BN=256, BK=128 bytes (= 2 ksteps of K=64),
// 512 threads / 8 waves (2x4), wave tile 128x64, mfma_i32_16x16x64_i8.
//
// Merged R4+R5 structure (m201-faithful):
//  - LDS: 2 x 64KB dbuf; per buf A[256][128] at +0, B[256][128] at +32768.
//    128B rows -> 8-way XOR chunk swizzle: LDS[r][c] = G[r][c ^ (r&7)]
//    (16B chunks), realized via inverse-permuted GLOBAL source + linear
//    global_load_lds dest (rule 21; verified 0 conflicts in R4).
//  - 8 phases per K128-iter, 8 MFMA each (quadrant x kstep); reads
//    6/4/2/0 per half; stage 2 gll/phase in P1-P4 (tile t+1 -> other buf,
//    youngest load has >=4 phases to land).
//  - ONE barrier per phase (pre-MFMA; reads of stable buf can issue right
//    after previous MFMA cluster). ONE vmcnt(0)+barrier per iter boundary.
// Output: int32 elements.
// ---------------------------------------------------------------------------
__global__ __launch_bounds__(512, 2) void gemm_i8_gelu_q_kernel(
    const uint8_t* __restrict__ x8, const uint8_t* __restrict__ w8,
    const float* __restrict__ bias, const float* __restrict__ pa,
    const float* __restrict__ pb, int* __restrict__ out) {
  __shared__ char sm[131072];

  const int tid = threadIdx.x;
  const int l   = tid & 63;
  const int wv  = tid >> 6;
  const int wr  = wv >> 2;             // 0..1  (M wave row)
  const int wc  = wv & 3;              // 0..3  (N wave col)
  const int lr  = l & 15;              // fragment row
  const int lg  = l >> 4;              // k-group 0..3 (16B chunk in K=64)

  // XCD-aware bijective swizzle (512 blocks % 8 == 0)
  int id = blockIdx.x;
  int wg = (id & 7) * 64 + (id >> 3);
  const int m0 = (wg >> 4) * 256;      // 32 row-bands
  const int n0 = (wg & 15) * 256;      // 16 col-bands

  const float av = pa[0];
  const float bv = pb[0];

  // ---- staging addressing (R4-verified): wave wv + instr J covers rows
  // wv*32 + J*8 + (l>>3); LDS linear dest; source chunk inverse-swizzled.
  const int grow = (wv << 5) + (l >> 3);
  const int gch  = ((l & 7) ^ ((l >> 3) & 7)) << 4;
  const uint8_t* gA = x8 + (size_t)(m0 + grow) * INF + gch;
  const uint8_t* gB = w8 + (size_t)(n0 + grow) * INF + gch;
  const int dwv = wv * 4096;           // + J*1024 (+32768 for B, +bo for buf)

  // ---- fragment read offsets: frag (m|n, kstep s) at row*128 + swz slot
  int aoff[8], boff[4], sb0, sb1;
#pragma unroll
  for (int m = 0; m < 8; ++m) aoff[m] = (wr * 128 + m * 16 + lr) * 128;
#pragma unroll
  for (int n = 0; n < 4; ++n) boff[n] = 32768 + (wc * 64 + n * 16 + lr) * 128;
  sb0 = ((0 + lg) ^ (l & 7)) << 4;
  sb1 = ((4 + lg) ^ (l & 7)) << 4;

  v4i acc[8][4];
#pragma unroll
  for (int m = 0; m < 8; ++m)
#pragma unroll
    for (int n = 0; n < 4; ++n) acc[m][n] = (v4i){0, 0, 0, 0};

#define GLL(gsrc, ldst)                                                       \
  __builtin_amdgcn_global_load_lds(                                           \
      (const __attribute__((address_space(1))) unsigned*)(gsrc),              \
      (__attribute__((address_space(3))) unsigned*)(ldst), 16, 0, 0);

#define GLA(T, J) GLL(gA + (size_t)(J) * 8 * INF + (size_t)(T) * 128,         \
                      sm + (((T) & 1) << 16) + dwv + (J) * 1024)
#define GLB(T, J) GLL(gB + (size_t)(J) * 8 * INF + (size_t)(T) * 128,         \
                      sm + (((T) & 1) << 16) + 32768 + dwv + (J) * 1024)

#define LD(off) (*(const v4i*)(sbr + (off)))
#define MM(ACC, AF, BF)                                                       \
  ACC = __builtin_amdgcn_mfma_i32_16x16x64_i8(AF, BF, ACC, 0, 0, 0)

#define PH_BAR                                                                \
  barrier_fenced();                                                           \
  asm volatile("s_waitcnt lgkmcnt(0)" ::: "memory");                          \
  __builtin_amdgcn_s_setprio(1);
#define PH_END __builtin_amdgcn_s_setprio(0);

  // One K128-iter: 8 phases. DS: stage tile T=kt+1 (compile-time 0/1).
#define ITER(DS)                                                              \
  {                                                                           \
    const char* sbr = sm + ((kt & 1) << 16);                                  \
    const int T = kt + 1;                                                     \
    v4i A0[4], A4[4], B0[2], B2[2];                                           \
    /* ---------- kstep 0 ---------- */                                       \
    A0[0] = LD(aoff[0] + sb0); A0[1] = LD(aoff[1] + sb0);                     \
    A0[2] = LD(aoff[2] + sb0); A0[3] = LD(aoff[3] + sb0);                     \
    B0[0] = LD(boff[0] + sb0); B0[1] = LD(boff[1] + sb0);                     \
    if (DS) { GLA(T, 0); GLA(T, 1); }                                         \
    PH_BAR /* P1: m0-3 x n0-1 */                                              \
    MM(acc[0][0], A0[0], B0[0]); MM(acc[0][1], A0[0], B0[1]);                 \
    MM(acc[1][0], A0[1], B0[0]); MM(acc[1][1], A0[1], B0[1]);                 \
    MM(acc[2][0], A0[2], B0[0]); MM(acc[2][1], A0[2], B0[1]);                 \
    MM(acc[3][0], A0[3], B0[0]); MM(acc[3][1], A0[3], B0[1]);                 \
    PH_END                                                                    \
    A4[0] = LD(aoff[4] + sb0); A4[1] = LD(aoff[5] + sb0);                     \
    A4[2] = LD(aoff[6] + sb0); A4[3] = LD(aoff[7] + sb0);                     \
    if (DS) { GLA(T, 2); GLA(T, 3); }                                         \
    PH_BAR /* P2: m4-7 x n0-1 */                                              \
    MM(acc[4][0], A4[0], B0[0]); MM(acc[4][1], A4[0], B0[1]);                 \
    MM(acc[5][0], A4[1], B0[0]); MM(acc[5][1], A4[1], B0[1]);                 \
    MM(acc[6][0], A4[2], B0[0]); MM(acc[6][1], A4[2], B0[1]);                 \
    MM(acc[7][0], A4[3], B0[0]); MM(acc[7][1], A4[3], B0[1]);                 \
    PH_END                                                                    \
    B2[0] = LD(boff[2] + sb0); B2[1] = LD(boff[3] + sb0);                     \
    if (DS) { GLB(T, 0); GLB(T, 1); }                                         \
    PH_BAR /* P3: m0-3 x n2-3 */                                              \
    MM(acc[0][2], A0[0], B2[0]); MM(acc[0][3], A0[0], B2[1]);                 \
    MM(acc[1][2], A0[1], B2[0]); MM(acc[1][3], A0[1], B2[1]);                 \
    MM(acc[2][2], A0[2], B2[0]); MM(acc[2][3], A0[2], B2[1]);                 \
    MM(acc[3][2], A0[3], B2[0]); MM(acc[3][3], A0[3], B2[1]);                 \
    PH_END                                                                    \
    if (DS) { GLB(T, 2); GLB(T, 3); }                                         \
    PH_BAR /* P4: m4-7 x n2-3 */                                              \
    MM(acc[4][2], A4[0], B2[0]); MM(acc[4][3], A4[0], B2[1]);                 \
    MM(acc[5][2], A4[1], B2[0]); MM(acc[5][3], A4[1], B2[1]);                 \
    MM(acc[6][2], A4[2], B2[0]); MM(acc[6][3], A4[2], B2[1]);                 \
    MM(acc[7][2], A4[3], B2[0]); MM(acc[7][3], A4[3], B2[1]);                 \
    PH_END                                                                    \
    /* ---------- kstep 1 (no staging) ---------- */                          \
    A0[0] = LD(aoff[0] + sb1); A0[1] = LD(aoff[1] + sb1);                     \
    A0[2] = LD(aoff[2] + sb1); A0[3] = LD(aoff[3] + sb1);                     \
    B0[0] = LD(boff[0] + sb1); B0[1] = LD(boff[1] + sb1);                     \
    PH_BAR /* P5 */                                                           \
    MM(acc[0][0], A0[0], B0[0]); MM(acc[0][1], A0[0], B0[1]);                 \
    MM(acc[1][0], A0[1], B0[0]); MM(acc[1][1], A0[1], B0[1]);                 \
    MM(acc[2][0], A0[2], B0[0]); MM(acc[2][1], A0[2], B0[1]);                 \
    MM(acc[3][0], A0[3], B0[0]); MM(acc[3][1], A0[3], B0[1]);                 \
    PH_END                                                                    \
    A4[0] = LD(aoff[4] + sb1); A4[1] = LD(aoff[5] + sb1);                     \
    A4[2] = LD(aoff[6] + sb1); A4[3] = LD(aoff[7] + sb1);                     \
    PH_BAR /* P6 */                                                           \
    MM(acc[4][0], A4[0], B0[0]); MM(acc[4][1], A4[0], B0[1]);                 \
    MM(acc[5][0], A4[1], B0[0]); MM(acc[5][1], A4[1], B0[1]);                 \
    MM(acc[6][0], A4[2], B0[0]); MM(acc[6][1], A4[2], B0[1]);                 \
    MM(acc[7][0], A4[3], B0[0]); MM(acc[7][1], A4[3], B0[1]);                 \
    PH_END                                                                    \
    B2[0] = LD(boff[2] + sb1); B2[1] = LD(boff[3] + sb1);                     \
    PH_BAR /* P7 */                                                           \
    MM(acc[0][2], A0[0], B2[0]); MM(acc[0][3], A0[0], B2[1]);                 \
    MM(acc[1][2], A0[1], B2[0]); MM(acc[1][3], A0[1], B2[1]);                 \
    MM(acc[2][2], A0[2], B2[0]); MM(acc[2][3], A0[2], B2[1]);                 \
    MM(acc[3][2], A0[3], B2[0]); MM(acc[3][3], A0[3], B2[1]);                 \
    PH_END                                                                    \
    PH_BAR /* P8 */                                                           \
    MM(acc[4][2], A4[0], B2[0]); MM(acc[4][3], A4[0], B2[1]);                 \
    MM(acc[5][2], A4[1], B2[0]); MM(acc[5][3], A4[1], B2[1]);                 \
    MM(acc[6][2], A4[2], B2[0]); MM(acc[6][3], A4[2], B2[1]);                 \
    MM(acc[7][2], A4[3], B2[0]); MM(acc[7][3], A4[3], B2[1]);                 \
    PH_END                                                                    \
    /* ---------- boundary: tile T landed; publish ---------- */              \
    if (DS) { asm volatile("s_waitcnt vmcnt(0)" ::: "memory"); }              \
    barrier_fenced();                                                         \
  }

  // prologue: stage tile 0, publish
  GLA(0, 0); GLA(0, 1); GLA(0, 2); GLA(0, 3);
  GLB(0, 0); GLB(0, 1); GLB(0, 2); GLB(0, 3);
  asm volatile("s_waitcnt vmcnt(0)" ::: "memory");
  barrier_fenced();

#pragma unroll 1
  for (int kt = 0; kt < 31; ++kt) ITER(1)
  {
    const int kt = 31;
    ITER(0)
  }

  // ---- epilogue: dequant + bias + exact GeLU + requant, write INT32 ----
  float bvals[4];
#pragma unroll
  for (int n = 0; n < 4; ++n) bvals[n] = bias[n0 + wc * 64 + n * 16 + lr];

#pragma unroll
  for (int m = 0; m < 8; ++m) {
    int rowb = m0 + wr * 128 + m * 16 + lg * 4;
#pragma unroll
    for (int q = 0; q < 4; ++q) {
      size_t rb = (size_t)(rowb + q) * OUTF;
#pragma unroll
      for (int n = 0; n < 4; ++n) {
        float f = fmaf(av, (float)acc[m][n][q], bvals[n]);
        float g = gelu_exact(f);
        float r = __builtin_rintf(g * bv);
        r = fminf(fmaxf(r, -128.0f), 127.0f);
        out[rb + (size_t)(n0 + wc * 64 + n * 16 + lr)] = (int)r;
      }
    }
  }
#undef GLL
#undef GLA
#undef GLB
#undef LD
#undef MM
#undef PH_BAR
#undef PH_END
#undef ITER
}

// ---------------------------------------------------------------------------
extern "C" void kernel_launch(void* const* d_in, const int* in_sizes, int n_in,
                              void* d_out, int out_size, void* d_ws,
                              size_t ws_size, hipStream_t stream) {
  const int*   xi   = (const int*)d_in[0];
  const int*   wi   = (const int*)d_in[1];
  const float* bias = (const float*)d_in[2];
  const float* pa   = (const float*)d_in[3];
  const float* pb   = (const float*)d_in[4];
  int*         out  = (int*)d_out;

  uint8_t* x8 = (uint8_t*)d_ws;                         // 33554432 B
  uint8_t* w8 = x8 + (size_t)TOKENS * INF;              // 16777216 B
  // requires ws_size >= 50331648

  pack_i8_kernel<<<2048, 256, 0, stream>>>(xi, wi, x8, w8);

  dim3 grid((TOKENS / 256) * (OUTF / 256));             // 512 blocks
  gemm_i8_gelu_q_kernel<<<grid, 512, 0, stream>>>(x8, w8, bias, pa, pb, out);
}

// Round 8
// 388.020 us; speedup vs baseline: 1.0962x; 1.0314x over previous
//
#include <hip/hip_runtime.h>
#include <cstdint>
#include <cstddef>

// Problem constants (fixed by the reference)
#define TOKENS 8192
#define INF    4096
#define OUTF   4096

typedef int v4i __attribute__((ext_vector_type(4)));

// ---------------------------------------------------------------------------
// Kernel 1: pack int32 -> int8 into workspace (x8 then w8, row-major).
// Thread t handles 4 CONSECUTIVE int4-chunks -> one 16B packed store.
// Reads 64B contiguous/thread (4-deep ILP), writes int4 (fully coalesced).
// ---------------------------------------------------------------------------
__global__ __launch_bounds__(256) void pack_i8_kernel(
    const int* __restrict__ xi, const int* __restrict__ wi,
    uint8_t* __restrict__ x8, uint8_t* __restrict__ w8) {
  const int NXT = (TOKENS * INF) / 16;   // 2097152 x-tasks (16 ints each)
  const int NT  = 2048 * 256;            // 524288 threads
  int tid = blockIdx.x * 256 + threadIdx.x;
#pragma unroll 1
  for (int g = 0; g < 6; ++g) {          // 6 * 524288 = 3145728 tasks total
    int t = g * NT + tid;
    const int4* s;
    int4* d;
    if (t < NXT) {
      s = (const int4*)xi + 4 * (size_t)t;
      d = (int4*)x8 + t;
    } else {
      int t2 = t - NXT;
      s = (const int4*)wi + 4 * (size_t)t2;
      d = (int4*)w8 + t2;
    }
    int4 v0 = s[0], v1 = s[1], v2 = s[2], v3 = s[3];
    int4 p;
    p.x = (v0.x & 255) | ((v0.y & 255) << 8) | ((v0.z & 255) << 16) | (v0.w << 24);
    p.y = (v1.x & 255) | ((v1.y & 255) << 8) | ((v1.z & 255) << 16) | (v1.w << 24);
    p.z = (v2.x & 255) | ((v2.y & 255) << 8) | ((v2.z & 255) << 16) | (v2.w << 24);
    p.w = (v3.x & 255) | ((v3.y & 255) << 8) | ((v3.z & 255) << 16) | (v3.w << 24);
    *d = p;
  }
}

// ---------------------------------------------------------------------------
// Branchless exact-GeLU via Abramowitz-Stegun 7.1.26 erf (|err| <= 1.5e-7).
// ---------------------------------------------------------------------------
__device__ __forceinline__ float gelu_exact(float y) {
  float x = y * 0.70710678118654752f;   // y / sqrt(2)
  float s = fabsf(x);
  float t = __builtin_amdgcn_rcpf(fmaf(s, 0.3275911f, 1.0f));
  float p = t * fmaf(t, fmaf(t, fmaf(t, fmaf(t, 1.061405429f, -1.453152027f),
                                     1.421413741f), -0.284496736f),
                     0.254829592f);
  float e = __expf(-s * s);
  float er = fmaf(-p, e, 1.0f);         // erf(|x|)
  er = copysignf(er, x);
  return 0.5f * y * (1.0f + er);
}

__device__ __forceinline__ void barrier_fenced() {
  asm volatile("" ::: "memory");
  __builtin_amdgcn_s_barrier();
  asm volatile("" ::: "memory");
}

// ---------------------------------------------------------------------------
// Kernel 2: int8 GEMM, BM=BN=256, BK=128 bytes (2 ksteps of K=64),
// 512 threads / 8 waves (2x4), wave tile 128x64, mfma_i32_16x16x64_i8.
//
// Barrier-LIGHT schedule (R7 post-mortem: i8 MFMA is 4x bf16 duration, so
// lockstep phase barriers exposed LDS latency instead of hiding it; with
// 2 waves/SIMD, free-running waves cover each other via TLP - m114):
//  - LDS: 2 x 64KB dbuf; A[256][128] +0, B[256][128] +32768 per buf.
//    8-way XOR chunk swizzle LDS[r][c]=G[r][c^(r&7)] via inverse-permuted
//    global source + linear gll dest (rule 21; 0 conflicts measured R4/R7).
//  - Per K128-iter: 8 gll (tile kt+1 -> other buf) issued at iter TOP
//    (~full iter of slack); 24 ds_reads + 64 MFMA compiler-scheduled
//    (fine-grained lgkmcnt auto-inserted); setprio(1) around each
//    8-MFMA cluster; ONE slack-covered vmcnt(0) + ONE raw barrier per iter.
//  - Race safety: intra-iter reads hit stable buf[kt&1]; gll writes
//    buf[(kt+1)&1], last read in iter kt-1 whose reads completed before
//    their consuming MFMAs, which precede the boundary barrier.
// Output: int32 elements.
// ---------------------------------------------------------------------------
__global__ __launch_bounds__(512, 2) void gemm_i8_gelu_q_kernel(
    const uint8_t* __restrict__ x8, const uint8_t* __restrict__ w8,
    const float* __restrict__ bias, const float* __restrict__ pa,
    const float* __restrict__ pb, int* __restrict__ out) {
  __shared__ char sm[131072];

  const int tid = threadIdx.x;
  const int l   = tid & 63;
  const int wv  = tid >> 6;
  const int wr  = wv >> 2;             // 0..1  (M wave row)
  const int wc  = wv & 3;              // 0..3  (N wave col)
  const int lr  = l & 15;              // fragment row
  const int lg  = l >> 4;              // k-group 0..3 (16B chunk in K=64)

  // XCD-aware bijective swizzle (512 blocks % 8 == 0)
  int id = blockIdx.x;
  int wg = (id & 7) * 64 + (id >> 3);
  const int m0 = (wg >> 4) * 256;      // 32 row-bands
  const int n0 = (wg & 15) * 256;      // 16 col-bands

  const float av = pa[0];
  const float bv = pb[0];

  // ---- staging addressing (R4-verified): wave wv + instr J covers rows
  // wv*32 + J*8 + (l>>3); LDS linear dest; source chunk inverse-swizzled.
  const int grow = (wv << 5) + (l >> 3);
  const int gch  = ((l & 7) ^ ((l >> 3) & 7)) << 4;
  const uint8_t* gA = x8 + (size_t)(m0 + grow) * INF + gch;
  const uint8_t* gB = w8 + (size_t)(n0 + grow) * INF + gch;
  const int dwv = wv * 4096;           // + J*1024 (+32768 for B, +bo for buf)

  // ---- fragment read offsets: frag (m|n, kstep s) at row*128 + swz slot
  int aoff[8], boff[4], sb0, sb1;
#pragma unroll
  for (int m = 0; m < 8; ++m) aoff[m] = (wr * 128 + m * 16 + lr) * 128;
#pragma unroll
  for (int n = 0; n < 4; ++n) boff[n] = 32768 + (wc * 64 + n * 16 + lr) * 128;
  sb0 = ((0 + lg) ^ (l & 7)) << 4;
  sb1 = ((4 + lg) ^ (l & 7)) << 4;

  v4i acc[8][4];
#pragma unroll
  for (int m = 0; m < 8; ++m)
#pragma unroll
    for (int n = 0; n < 4; ++n) acc[m][n] = (v4i){0, 0, 0, 0};

#define GLL(gsrc, ldst)                                                       \
  __builtin_amdgcn_global_load_lds(                                           \
      (const __attribute__((address_space(1))) unsigned*)(gsrc),              \
      (__attribute__((address_space(3))) unsigned*)(ldst), 16, 0, 0);

#define GLA(T, J) GLL(gA + (size_t)(J) * 8 * INF + (size_t)(T) * 128,         \
                      sm + (((T) & 1) << 16) + dwv + (J) * 1024)
#define GLB(T, J) GLL(gB + (size_t)(J) * 8 * INF + (size_t)(T) * 128,         \
                      sm + (((T) & 1) << 16) + 32768 + dwv + (J) * 1024)

#define LD(off) (*(const v4i*)(sbr + (off)))
#define MM(ACC, AF, BF)                                                       \
  ACC = __builtin_amdgcn_mfma_i32_16x16x64_i8(AF, BF, ACC, 0, 0, 0)

  // One K64-kstep: 4 setprio-wrapped clusters of 8 MFMA (quadrants).
#define KSTEP                                                                 \
  __builtin_amdgcn_s_setprio(1);                                              \
  MM(acc[0][0], A0[0], B0[0]); MM(acc[0][1], A0[0], B0[1]);                   \
  MM(acc[1][0], A0[1], B0[0]); MM(acc[1][1], A0[1], B0[1]);                   \
  MM(acc[2][0], A0[2], B0[0]); MM(acc[2][1], A0[2], B0[1]);                   \
  MM(acc[3][0], A0[3], B0[0]); MM(acc[3][1], A0[3], B0[1]);                   \
  __builtin_amdgcn_s_setprio(0);                                              \
  __builtin_amdgcn_s_setprio(1);                                              \
  MM(acc[4][0], A4[0], B0[0]); MM(acc[4][1], A4[0], B0[1]);                   \
  MM(acc[5][0], A4[1], B0[0]); MM(acc[5][1], A4[1], B0[1]);                   \
  MM(acc[6][0], A4[2], B0[0]); MM(acc[6][1], A4[2], B0[1]);                   \
  MM(acc[7][0], A4[3], B0[0]); MM(acc[7][1], A4[3], B0[1]);                   \
  __builtin_amdgcn_s_setprio(0);                                              \
  __builtin_amdgcn_s_setprio(1);                                              \
  MM(acc[0][2], A0[0], B2[0]); MM(acc[0][3], A0[0], B2[1]);                   \
  MM(acc[1][2], A0[1], B2[0]); MM(acc[1][3], A0[1], B2[1]);                   \
  MM(acc[2][2], A0[2], B2[0]); MM(acc[2][3], A0[2], B2[1]);                   \
  MM(acc[3][2], A0[3], B2[0]); MM(acc[3][3], A0[3], B2[1]);                   \
  __builtin_amdgcn_s_setprio(0);                                              \
  __builtin_amdgcn_s_setprio(1);                                              \
  MM(acc[4][2], A4[0], B2[0]); MM(acc[4][3], A4[0], B2[1]);                   \
  MM(acc[5][2], A4[1], B2[0]); MM(acc[5][3], A4[1], B2[1]);                   \
  MM(acc[6][2], A4[2], B2[0]); MM(acc[6][3], A4[2], B2[1]);                   \
  MM(acc[7][2], A4[3], B2[0]); MM(acc[7][3], A4[3], B2[1]);                   \
  __builtin_amdgcn_s_setprio(0);

  // One K128-iter. DS: stage tile kt+1 (compile-time 0/1).
#define ITER(DS)                                                              \
  {                                                                           \
    const char* sbr = sm + ((kt & 1) << 16);                                  \
    const int T = kt + 1;                                                     \
    v4i A0[4], A4[4], B0[2], B2[2];                                           \
    /* k0 critical frags first, then stage burst (max slack), then rest */    \
    A0[0] = LD(aoff[0] + sb0); A0[1] = LD(aoff[1] + sb0);                     \
    A0[2] = LD(aoff[2] + sb0); A0[3] = LD(aoff[3] + sb0);                     \
    B0[0] = LD(boff[0] + sb0); B0[1] = LD(boff[1] + sb0);                     \
    if (DS) {                                                                 \
      GLA(T, 0); GLA(T, 1); GLA(T, 2); GLA(T, 3);                             \
      GLB(T, 0); GLB(T, 1); GLB(T, 2); GLB(T, 3);                             \
    }                                                                         \
    A4[0] = LD(aoff[4] + sb0); A4[1] = LD(aoff[5] + sb0);                     \
    A4[2] = LD(aoff[6] + sb0); A4[3] = LD(aoff[7] + sb0);                     \
    B2[0] = LD(boff[2] + sb0); B2[1] = LD(boff[3] + sb0);                     \
    KSTEP                                                                     \
    A0[0] = LD(aoff[0] + sb1); A0[1] = LD(aoff[1] + sb1);                     \
    A0[2] = LD(aoff[2] + sb1); A0[3] = LD(aoff[3] + sb1);                     \
    B0[0] = LD(boff[0] + sb1); B0[1] = LD(boff[1] + sb1);                     \
    A4[0] = LD(aoff[4] + sb1); A4[1] = LD(aoff[5] + sb1);                     \
    A4[2] = LD(aoff[6] + sb1); A4[3] = LD(aoff[7] + sb1);                     \
    B2[0] = LD(boff[2] + sb1); B2[1] = LD(boff[3] + sb1);                     \
    KSTEP                                                                     \
    /* boundary: publish tile T (gll's ~full iter old -> vmcnt ~free) */      \
    if (DS) { asm volatile("s_waitcnt vmcnt(0)" ::: "memory"); }              \
    barrier_fenced();                                                         \
  }

  // prologue: stage tile 0, publish
  GLA(0, 0); GLA(0, 1); GLA(0, 2); GLA(0, 3);
  GLB(0, 0); GLB(0, 1); GLB(0, 2); GLB(0, 3);
  asm volatile("s_waitcnt vmcnt(0)" ::: "memory");
  barrier_fenced();

#pragma unroll 1
  for (int kt = 0; kt < 31; ++kt) ITER(1)
  {
    const int kt = 31;
    ITER(0)
  }

  // ---- epilogue: dequant + bias + exact GeLU + requant, write INT32 ----
  float bvals[4];
#pragma unroll
  for (int n = 0; n < 4; ++n) bvals[n] = bias[n0 + wc * 64 + n * 16 + lr];

#pragma unroll
  for (int m = 0; m < 8; ++m) {
    int rowb = m0 + wr * 128 + m * 16 + lg * 4;
#pragma unroll
    for (int q = 0; q < 4; ++q) {
      size_t rb = (size_t)(rowb + q) * OUTF;
#pragma unroll
      for (int n = 0; n < 4; ++n) {
        float f = fmaf(av, (float)acc[m][n][q], bvals[n]);
        float g = gelu_exact(f);
        float r = __builtin_rintf(g * bv);
        r = fminf(fmaxf(r, -128.0f), 127.0f);
        out[rb + (size_t)(n0 + wc * 64 + n * 16 + lr)] = (int)r;
      }
    }
  }
#undef GLL
#undef GLA
#undef GLB
#undef LD
#undef MM
#undef KSTEP
#undef ITER
}

// ---------------------------------------------------------------------------
extern "C" void kernel_launch(void* const* d_in, const int* in_sizes, int n_in,
                              void* d_out, int out_size, void* d_ws,
                              size_t ws_size, hipStream_t stream) {
  const int*   xi   = (const int*)d_in[0];
  const int*   wi   = (const int*)d_in[1];
  const float* bias = (const float*)d_in[2];
  const float* pa   = (const float*)d_in[3];
  const float* pb   = (const float*)d_in[4];
  int*         out  = (int*)d_out;

  uint8_t* x8 = (uint8_t*)d_ws;                         // 33554432 B
  uint8_t* w8 = x8 + (size_t)TOKENS * INF;              // 16777216 B
  // requires ws_size >= 50331648

  pack_i8_kernel<<<2048, 256, 0, stream>>>(xi, wi, x8, w8);

  dim3 grid((TOKENS / 256) * (OUTF / 256));             // 512 blocks
  gemm_i8_gelu_q_kernel<<<grid, 512, 0, stream>>>(x8, w8, bias, pa, pb, out);
}

// Round 9
// 385.562 us; speedup vs baseline: 1.1032x; 1.0064x over previous
//
#include <hip/hip_runtime.h>
#include <cstdint>
#include <cstddef>

// Problem constants (fixed by the reference)
#define TOKENS 8192
#define INF    4096
#define OUTF   4096

typedef int v4i __attribute__((ext_vector_type(4)));

// ---------------------------------------------------------------------------
// Kernel 1: pack int32 -> int8 into workspace (x8 then w8, row-major).
// Thread t handles 4 consecutive int4-chunks -> one 16B packed store.
// ---------------------------------------------------------------------------
__global__ __launch_bounds__(256) void pack_i8_kernel(
    const int* __restrict__ xi, const int* __restrict__ wi,
    uint8_t* __restrict__ x8, uint8_t* __restrict__ w8) {
  const int NXT = (TOKENS * INF) / 16;   // 2097152 x-tasks (16 ints each)
  const int NT  = 2048 * 256;            // 524288 threads
  int tid = blockIdx.x * 256 + threadIdx.x;
#pragma unroll 1
  for (int g = 0; g < 6; ++g) {          // 6 * 524288 = 3145728 tasks total
    int t = g * NT + tid;
    const int4* s;
    int4* d;
    if (t < NXT) {
      s = (const int4*)xi + 4 * (size_t)t;
      d = (int4*)x8 + t;
    } else {
      int t2 = t - NXT;
      s = (const int4*)wi + 4 * (size_t)t2;
      d = (int4*)w8 + t2;
    }
    int4 v0 = s[0], v1 = s[1], v2 = s[2], v3 = s[3];
    int4 p;
    p.x = (v0.x & 255) | ((v0.y & 255) << 8) | ((v0.z & 255) << 16) | (v0.w << 24);
    p.y = (v1.x & 255) | ((v1.y & 255) << 8) | ((v1.z & 255) << 16) | (v1.w << 24);
    p.z = (v2.x & 255) | ((v2.y & 255) << 8) | ((v2.z & 255) << 16) | (v2.w << 24);
    p.w = (v3.x & 255) | ((v3.y & 255) << 8) | ((v3.z & 255) << 16) | (v3.w << 24);
    *d = p;
  }
}

// ---------------------------------------------------------------------------
// Branchless exact-GeLU via Abramowitz-Stegun 7.1.26 erf (|err| <= 1.5e-7).
// ---------------------------------------------------------------------------
__device__ __forceinline__ float gelu_exact(float y) {
  float x = y * 0.70710678118654752f;   // y / sqrt(2)
  float s = fabsf(x);
  float t = __builtin_amdgcn_rcpf(fmaf(s, 0.3275911f, 1.0f));
  float p = t * fmaf(t, fmaf(t, fmaf(t, fmaf(t, 1.061405429f, -1.453152027f),
                                     1.421413741f), -0.284496736f),
                     0.254829592f);
  float e = __expf(-s * s);
  float er = fmaf(-p, e, 1.0f);         // erf(|x|)
  er = copysignf(er, x);
  return 0.5f * y * (1.0f + er);
}

__device__ __forceinline__ void barrier_fenced() {
  asm volatile("" ::: "memory");
  __builtin_amdgcn_s_barrier();
  asm volatile("" ::: "memory");
}

// ---------------------------------------------------------------------------
// Kernel 2: int8 GEMM, BM=BN=256, BK=128 bytes (2 ksteps of K=64),
// 512 threads / 8 waves (2x4), wave tile 128x64, mfma_i32_16x16x64_i8.
//
// R8 post-mortem: LDS-read phase and MFMA phase were SERIAL (5362 cy/iter
// = 2611 MFMA + ~2800 LDS; MfmaUtil 41% = 2611/5362). This round forces
// intra-wave LDS||MFMA overlap: k1's reads (separate regs) are placed
// BETWEEN k0's MFMA clusters, pinned by a sched_group_barrier chain.
// Sync rotation unchanged from R8 (proven race-free):
//   [vmcnt(0) tile kt landed; barrier; gll burst tile kt+1; body]
// 8-way XOR chunk swizzle via inverse-permuted global source + linear gll
// dest (rule 21; 0 conflicts measured R4/R7/R8). Output: int32.
// ---------------------------------------------------------------------------
__global__ __launch_bounds__(512, 2) void gemm_i8_gelu_q_kernel(
    const uint8_t* __restrict__ x8, const uint8_t* __restrict__ w8,
    const float* __restrict__ bias, const float* __restrict__ pa,
    const float* __restrict__ pb, int* __restrict__ out) {
  __shared__ char sm[131072];

  const int tid = threadIdx.x;
  const int l   = tid & 63;
  const int wv  = tid >> 6;
  const int wr  = wv >> 2;             // 0..1  (M wave row)
  const int wc  = wv & 3;              // 0..3  (N wave col)
  const int lr  = l & 15;              // fragment row
  const int lg  = l >> 4;              // k-group 0..3 (16B chunk in K=64)

  // XCD-aware bijective swizzle (512 blocks % 8 == 0)
  int id = blockIdx.x;
  int wg = (id & 7) * 64 + (id >> 3);
  const int m0 = (wg >> 4) * 256;      // 32 row-bands
  const int n0 = (wg & 15) * 256;      // 16 col-bands

  const float av = pa[0];
  const float bv = pb[0];

  // ---- staging addressing (R4-verified): wave wv + instr J covers rows
  // wv*32 + J*8 + (l>>3); LDS linear dest; source chunk inverse-swizzled.
  const int grow = (wv << 5) + (l >> 3);
  const int gch  = ((l & 7) ^ ((l >> 3) & 7)) << 4;
  const uint8_t* gA = x8 + (size_t)(m0 + grow) * INF + gch;
  const uint8_t* gB = w8 + (size_t)(n0 + grow) * INF + gch;
  const int dwv = wv * 4096;           // + J*1024 (+32768 for B, +bo for buf)

  // ---- fragment read offsets: frag (m|n, kstep s) at row*128 + swz slot
  int aoff[8], boff[4], sb0, sb1;
#pragma unroll
  for (int m = 0; m < 8; ++m) aoff[m] = (wr * 128 + m * 16 + lr) * 128;
#pragma unroll
  for (int n = 0; n < 4; ++n) boff[n] = 32768 + (wc * 64 + n * 16 + lr) * 128;
  sb0 = ((0 + lg) ^ (l & 7)) << 4;
  sb1 = ((4 + lg) ^ (l & 7)) << 4;

  v4i acc[8][4];
#pragma unroll
  for (int m = 0; m < 8; ++m)
#pragma unroll
    for (int n = 0; n < 4; ++n) acc[m][n] = (v4i){0, 0, 0, 0};

#define GLL(gsrc, ldst)                                                       \
  __builtin_amdgcn_global_load_lds(                                           \
      (const __attribute__((address_space(1))) unsigned*)(gsrc),              \
      (__attribute__((address_space(3))) unsigned*)(ldst), 16, 0, 0);

#define GLA(T, J) GLL(gA + (size_t)(J) * 8 * INF + (size_t)(T) * 128,         \
                      sm + (((T) & 1) << 16) + dwv + (J) * 1024)
#define GLB(T, J) GLL(gB + (size_t)(J) * 8 * INF + (size_t)(T) * 128,         \
                      sm + (((T) & 1) << 16) + 32768 + dwv + (J) * 1024)

#define LD(off) (*(const v4i*)(sbr + (off)))
#define MM(ACC, AF, BF)                                                       \
  ACC = __builtin_amdgcn_mfma_i32_16x16x64_i8(AF, BF, ACC, 0, 0, 0)

  // One cluster: 4 A-frags x 2 B-frags -> 8 MFMA, setprio-wrapped.
#define CL(AF, BF, MB, NB)                                                    \
  __builtin_amdgcn_s_setprio(1);                                              \
  MM(acc[(MB)+0][(NB)+0], AF[0], BF[0]); MM(acc[(MB)+0][(NB)+1], AF[0], BF[1]);\
  MM(acc[(MB)+1][(NB)+0], AF[1], BF[0]); MM(acc[(MB)+1][(NB)+1], AF[1], BF[1]);\
  MM(acc[(MB)+2][(NB)+0], AF[2], BF[0]); MM(acc[(MB)+2][(NB)+1], AF[2], BF[1]);\
  MM(acc[(MB)+3][(NB)+0], AF[3], BF[0]); MM(acc[(MB)+3][(NB)+1], AF[3], BF[1]);\
  __builtin_amdgcn_s_setprio(0);

  // One K128-iter. DS: stage tile kt+1 (compile-time 0/1).
#define ITER(DS)                                                              \
  {                                                                           \
    const char* sbr = sm + ((kt & 1) << 16);                                  \
    const int T = kt + 1;                                                     \
    asm volatile("s_waitcnt vmcnt(0)" ::: "memory"); /* tile kt landed */     \
    barrier_fenced();     /* cross-wave publish; prev body reads done */      \
    if (DS) {                                                                 \
      GLA(T, 0); GLA(T, 1); GLA(T, 2); GLA(T, 3);                             \
      GLB(T, 0); GLB(T, 1); GLB(T, 2); GLB(T, 3);                             \
    }                                                                         \
    v4i a0[4], a4[4], b0[2], b2[2];   /* k0 frags */                          \
    v4i c0[4], c4[4], d0[2], d2[2];   /* k1 frags (separate regs) */          \
    a0[0] = LD(aoff[0] + sb0); a0[1] = LD(aoff[1] + sb0);                     \
    a0[2] = LD(aoff[2] + sb0); a0[3] = LD(aoff[3] + sb0);                     \
    b0[0] = LD(boff[0] + sb0); b0[1] = LD(boff[1] + sb0);                     \
    a4[0] = LD(aoff[4] + sb0); a4[1] = LD(aoff[5] + sb0);                     \
    a4[2] = LD(aoff[6] + sb0); a4[3] = LD(aoff[7] + sb0);                     \
    b2[0] = LD(boff[2] + sb0); b2[1] = LD(boff[3] + sb0);                     \
    CL(a0, b0, 0, 0)                                                          \
    c0[0] = LD(aoff[0] + sb1); c0[1] = LD(aoff[1] + sb1);                     \
    c0[2] = LD(aoff[2] + sb1); c0[3] = LD(aoff[3] + sb1);                     \
    d0[0] = LD(boff[0] + sb1); d0[1] = LD(boff[1] + sb1);                     \
    CL(a4, b0, 4, 0)                                                          \
    CL(a0, b2, 0, 2)                                                          \
    c4[0] = LD(aoff[4] + sb1); c4[1] = LD(aoff[5] + sb1);                     \
    c4[2] = LD(aoff[6] + sb1); c4[3] = LD(aoff[7] + sb1);                     \
    d2[0] = LD(boff[2] + sb1); d2[1] = LD(boff[3] + sb1);                     \
    CL(a4, b2, 4, 2)                                                          \
    CL(c0, d0, 0, 0)                                                          \
    CL(c4, d0, 4, 0)                                                          \
    CL(c0, d2, 0, 2)                                                          \
    CL(c4, d2, 4, 2)                                                          \
    /* pin emission: gll, k0 reads, CL1, k1a reads, CL2-3, k1b reads, rest */ \
    if (DS) { __builtin_amdgcn_sched_group_barrier(0x020, 8, 0); }            \
    __builtin_amdgcn_sched_group_barrier(0x100, 12, 0);                       \
    __builtin_amdgcn_sched_group_barrier(0x008, 8, 0);                        \
    __builtin_amdgcn_sched_group_barrier(0x100, 6, 0);                        \
    __builtin_amdgcn_sched_group_barrier(0x008, 16, 0);                       \
    __builtin_amdgcn_sched_group_barrier(0x100, 6, 0);                        \
    __builtin_amdgcn_sched_group_barrier(0x008, 40, 0);                       \
  }

  // prologue: stage tile 0 (iter 0's vmcnt(0)+barrier publishes it)
  GLA(0, 0); GLA(0, 1); GLA(0, 2); GLA(0, 3);
  GLB(0, 0); GLB(0, 1); GLB(0, 2); GLB(0, 3);

#pragma unroll 1
  for (int kt = 0; kt < 31; ++kt) ITER(1)
  {
    const int kt = 31;
    ITER(0)
  }

  // ---- epilogue: dequant + bias + exact GeLU + requant, write INT32 ----
  float bvals[4];
#pragma unroll
  for (int n = 0; n < 4; ++n) bvals[n] = bias[n0 + wc * 64 + n * 16 + lr];

#pragma unroll
  for (int m = 0; m < 8; ++m) {
    int rowb = m0 + wr * 128 + m * 16 + lg * 4;
#pragma unroll
    for (int q = 0; q < 4; ++q) {
      size_t rb = (size_t)(rowb + q) * OUTF;
#pragma unroll
      for (int n = 0; n < 4; ++n) {
        float f = fmaf(av, (float)acc[m][n][q], bvals[n]);
        float g = gelu_exact(f);
        float r = __builtin_rintf(g * bv);
        r = fminf(fmaxf(r, -128.0f), 127.0f);
        out[rb + (size_t)(n0 + wc * 64 + n * 16 + lr)] = (int)r;
      }
    }
  }
#undef GLL
#undef GLA
#undef GLB
#undef LD
#undef MM
#undef CL
#undef ITER
}

// ---------------------------------------------------------------------------
extern "C" void kernel_launch(void* const* d_in, const int* in_sizes, int n_in,
                              void* d_out, int out_size, void* d_ws,
                              size_t ws_size, hipStream_t stream) {
  const int*   xi   = (const int*)d_in[0];
  const int*   wi   = (const int*)d_in[1];
  const float* bias = (const float*)d_in[2];
  const float* pa   = (const float*)d_in[3];
  const float* pb   = (const float*)d_in[4];
  int*         out  = (int*)d_out;

  uint8_t* x8 = (uint8_t*)d_ws;                         // 33554432 B
  uint8_t* w8 = x8 + (size_t)TOKENS * INF;              // 16777216 B
  // requires ws_size >= 50331648

  pack_i8_kernel<<<2048, 256, 0, stream>>>(xi, wi, x8, w8);

  dim3 grid((TOKENS / 256) * (OUTF / 256));             // 512 blocks
  gemm_i8_gelu_q_kernel<<<grid, 512, 0, stream>>>(x8, w8, bias, pa, pb, out);
}